// Round 2
// baseline (138.434 us; speedup 1.0000x reference)
//
#include <hip/hip_runtime.h>

// rmsdLoss via associative affine scan — R12.
// R11 fixed spills/staging (WRITE 8.25MB->64B, conflicts->0) but only -7%:
// still latency/instruction-bound (VALU 44%, HBM 11%). The cost is the
// 12-float affine Hillis-Steele scan (6 x {12 shfl + 12 sel + 39 FMA}) and
// the 8-step serial matrix chain.
// R12: scan state 12 -> 4+3 floats.
//  * Step rotation is exactly Rx(beta)Rz(alpha) with cos a=-ct, sin a=st,
//    cos b=ccv, sin b=scv (all already computed) -> step QUATERNION built
//    directly from half-angle sqrts (~12 ops, no matrix<->quat conversion;
//    EPS clip guarantees st>=1.4e-3 so no degeneracy).
//  * Local chunk compose: qmul chain (12cy/step dep latency vs ~30 matrix)
//    + per-step translation via quat-rotate; snapshots tl[k] as before.
//  * Quat scan: 6 x {4 shfl + 4 sel + 16 FMA}. Translations decouple into a
//    COMMUTATIVE add-scan: w = rot(q_excl, t_chunk) once, then 3-float sum
//    scan; exclusive = inclusive - own (no shuffle).
//  * Fold F0 = Rz(g) stays a quaternion (qG = qF x qE); one quat->matrix
//    (2/|q|^2 trick, no sqrt) for the final 8 position transforms.
//  * Compose guards dropped: only lane 127's tail steps are garbage and its
//    inclusive values are the top of both scans (flow nowhere); publish/diff
//    remain guarded. Cross-lane ops/thread: 84 -> 46.

#define LROW  4087
#define NSTEP 1021
#define NROW  2048
#define CHUNK 8
#define EPSF  1e-6f
#define INVMEAN (1.0f / (2048.0f * 1024.0f * 3.0f))

__device__ __forceinline__ float frcp(float x){ return __builtin_amdgcn_rcpf(x); }

struct Q { float w, x, y, z; };

// Hamilton product: R(a*b) = R(a)R(b)  (a applied AFTER in column convention;
// for our scan "A first then B" composes as qmul(A,B) matching C.M=A.M*B.M)
__device__ __forceinline__ Q qmul(const Q a, const Q b){
  Q c;
  c.w = a.w*b.w - a.x*b.x - a.y*b.y - a.z*b.z;
  c.x = a.w*b.x + a.x*b.w + a.y*b.z - a.z*b.y;
  c.y = a.w*b.y - a.x*b.z + a.y*b.w + a.z*b.x;
  c.z = a.w*b.z + a.x*b.y - a.y*b.x + a.z*b.w;
  return c;
}

// rotate v by unit quat q: v' = v + 2*(u x (u x v + w v)), u=(x,y,z)
__device__ __forceinline__ void qrot(const Q q, float vx, float vy, float vz,
                                     float& rx, float& ry, float& rz){
  const float cx = q.y*vz - q.z*vy + q.w*vx;
  const float cy = q.z*vx - q.x*vz + q.w*vy;
  const float cz = q.x*vy - q.y*vx + q.w*vz;
  rx = fmaf(2.f, q.y*cz - q.z*cy, vx);
  ry = fmaf(2.f, q.z*cx - q.x*cz, vy);
  rz = fmaf(2.f, q.x*cy - q.y*cx, vz);
}

__global__ void __launch_bounds__(256, 4)
rmsd_kernel(const float* __restrict__ pred, const float* __restrict__ targ,
            float* __restrict__ out){
  __shared__ float pos[128*25 + 8];   // pitch 25 (coprime w/ 32 banks): 12.8 KB
  __shared__ float Tbuf[2][8];        // per-chain half-0 totals: qw qx qy qz tx ty tz
  __shared__ float ini[3];            // pred a1x, a2x, a2y
  __shared__ float part;              // targ half-1 reduced partial

  const int row  = blockIdx.x;
  const int tid  = threadIdx.x;
  const int ln   = tid & 63;
  const int wv   = tid >> 6;          // 0..3
  const int c    = wv >> 1;           // 0 = pred, 1 = targ
  const int half = wv & 1;            // which half of the chain
  const int lid  = (half << 6) | ln;  // 0..127 lane-in-chain
  const int j0   = lid * CHUNK;       // first step owned (<= 1016)

  const float* __restrict__ v = (c ? targ : pred) + (size_t)row * LROW;
  const float cl = c ? 1e30f : 1.0f;  // reference clips pred only

  // broadcast fold inputs (wave-uniform -> scalar loads)
  const float rb0 = fminf(fmaxf(v[3064], -cl), cl);
  const float rd0 = fminf(fmaxf(v[2042], -cl), cl);
  const float rb1 = fminf(fmaxf(v[3065], -cl), cl);

  // ---- batch per-lane loads: 33 contiguous dwords, all independent ----
  float s0[CHUNK], s1[CHUNK], dd[CHUNK], bv[CHUNK+1];
  #pragma unroll
  for (int k = 0; k < CHUNK; ++k){
    s0[k] = v[2*(j0+k)];
    s1[k] = v[2*(j0+k)+1];
    dd[k] = v[2043 + j0 + k];
  }
  #pragma unroll
  for (int m = 0; m <= CHUNK; ++m){
    int ix = 3065 + j0 + m;
    if (ix > 4086) ix = 4086;        // tail lane clamp (garbage steps unused)
    bv[m] = v[ix];
  }
  #pragma unroll
  for (int m = 0; m <= CHUNK; ++m)
    bv[m] = fmaf(fminf(fmaxf(bv[m], -cl), cl), 1.05f, 1.95f);

  // ---- fused per-step build + local quat compose (UNGUARDED: lane 127's
  //      tail garbage is finite and its inclusive results flow nowhere) ----
  float tlx[CHUNK], tly[CHUNK], tlz[CHUNK];
  Q q;                                  // inclusive local quat
  #pragma unroll
  for (int k = 0; k < CHUNK; ++k){
    const float a0 = fminf(fmaxf(s0[k], -cl), cl);
    const float a1 = fminf(fmaxf(s1[k], -cl), cl);
    const float d  = fmaf(fminf(fmaxf(dd[k], -cl), cl), 1.75f, 3.25f);
    const float b1 = bv[k], b2 = bv[k+1];
    float ct = (b1*b1 + b2*b2 - d*d) * frcp(2.0f*b1*b2);
    ct = fminf(fmaxf(ct, -1.0f + EPSF), 1.0f - EPSF);
    const float st = sqrtf(fmaxf(1.0f - ct*ct, 0.0f));
    const float r2 = a0*a0 + a1*a1;
    const bool ok = r2 > 1e-36f;
    const float ir = ok ? frcp(sqrtf(r2)) : 0.0f;
    const float scv = a0 * ir;                 // sin(chi)
    const float ccv = ok ? a1 * ir : 1.0f;     // cos(chi)
    // step vector P (local frame)
    const float bst = b2 * st;
    const float Px = -b2*ct, Py = bst*ccv, Pz = bst*scv;
    // step quat = qx(beta) x qz(alpha); cos a=-ct, sin a=st; cos b=ccv, sin b=scv
    const float ca2 = sqrtf(0.5f*(1.0f - ct));                 // cos(a/2)
    const float sa2 = sqrtf(0.5f*(1.0f + ct));                 // sin(a/2)
    const float cb2 = sqrtf(fmaxf(0.5f*(1.0f + ccv), 0.0f));   // cos(b/2)
    const float sb2 = __builtin_copysignf(
                        sqrtf(fmaxf(0.5f*(1.0f - ccv), 0.0f)), scv); // sin(b/2)
    Q qs; qs.w = cb2*ca2; qs.x = sb2*ca2; qs.y = -sb2*sa2; qs.z = cb2*sa2;
    if (k == 0){
      tlx[0] = Px; tly[0] = Py; tlz[0] = Pz;
      q = qs;
    } else {
      float rx, ry, rz;
      qrot(q, Px, Py, Pz, rx, ry, rz);
      tlx[k] = tlx[k-1] + rx; tly[k] = tly[k-1] + ry; tlz[k] = tlz[k-1] + rz;
      q = qmul(q, qs);
    }
  }

  // ---- in-wave inclusive quat scan (Hillis-Steele, non-commutative) ----
  #pragma unroll
  for (int off = 1; off < 64; off <<= 1){
    Q o;
    o.w = __shfl_up(q.w, off); o.x = __shfl_up(q.x, off);
    o.y = __shfl_up(q.y, off); o.z = __shfl_up(q.z, off);
    const bool pr = (ln >= off);
    o.w = pr ? o.w : 1.0f; o.x = pr ? o.x : 0.0f;
    o.y = pr ? o.y : 0.0f; o.z = pr ? o.z : 0.0f;
    q = qmul(o, q);                      // earlier lanes applied first
  }

  // exclusive quat prefix
  Q qe;
  qe.w = __shfl_up(q.w, 1); qe.x = __shfl_up(q.x, 1);
  qe.y = __shfl_up(q.y, 1); qe.z = __shfl_up(q.z, 1);
  if (ln == 0){ qe.w = 1.0f; qe.x = 0.0f; qe.y = 0.0f; qe.z = 0.0f; }

  // ---- translation: w = R_excl * t_chunk, then commutative 3-float scan ----
  float wx, wy, wz;
  qrot(qe, tlx[CHUNK-1], tly[CHUNK-1], tlz[CHUNK-1], wx, wy, wz);
  float sx = wx, sy = wy, sz = wz;
  #pragma unroll
  for (int off = 1; off < 64; off <<= 1){
    const float ax = __shfl_up(sx, off);
    const float ay = __shfl_up(sy, off);
    const float az = __shfl_up(sz, off);
    if (ln >= off){ sx += ax; sy += ay; sz += az; }
  }
  float tex = sx - wx, tey = sy - wy, tez = sz - wz;   // exclusive prefix

  // half-0 publishes chain-half totals (lane 63 inclusive)
  if (half == 0 && ln == 63){
    Tbuf[c][0] = q.w; Tbuf[c][1] = q.x; Tbuf[c][2] = q.y; Tbuf[c][3] = q.z;
    Tbuf[c][4] = sx;  Tbuf[c][5] = sy;  Tbuf[c][6] = sz;
  }
  __syncthreads();

  if (half == 1){    // prepend half-0 total: E = T o E_local
    Q T; T.w = Tbuf[c][0]; T.x = Tbuf[c][1]; T.y = Tbuf[c][2]; T.z = Tbuf[c][3];
    float rx, ry, rz;
    qrot(T, tex, tey, tez, rx, ry, rz);
    tex = Tbuf[c][4] + rx; tey = Tbuf[c][5] + ry; tez = Tbuf[c][6] + rz;
    qe = qmul(T, qe);
  }

  // ---- fold (F0, a2): G.M = F0 * R(qe), G.t = a2 + F0 * te ----
  const float bl0 = fmaf(rb0, 1.05f, 1.95f);
  const float d0  = fmaf(rd0, 1.75f, 3.25f);
  const float b1f = fmaf(rb1, 1.05f, 1.95f);
  float ct0 = (bl0*bl0 + b1f*b1f - d0*d0) * frcp(2.0f*bl0*b1f);
  ct0 = fminf(fmaxf(ct0, -1.0f + EPSF), 1.0f - EPSF);
  const float st0 = sqrtf(fmaxf(1.0f - ct0*ct0, 0.0f));
  const float a1x = bl0;
  const float a2x = bl0 - b1f*ct0;
  const float a2y = b1f*st0;

  // qF = Rz(g), cos g = -ct0, sin g = st0 (g in [0,pi])
  const float cg2 = sqrtf(0.5f*(1.0f - ct0));
  const float sg2 = sqrtf(0.5f*(1.0f + ct0));
  Q g;                                   // qG = qF x qe  (qF = (cg2,0,0,sg2))
  g.w = cg2*qe.w - sg2*qe.z;
  g.x = cg2*qe.x - sg2*qe.y;
  g.y = cg2*qe.y + sg2*qe.x;
  g.z = cg2*qe.z + sg2*qe.w;

  const float gtx = a2x + (-ct0*tex - st0*tey);
  const float gty = a2y + ( st0*tex - ct0*tey);
  const float gtz = tez;

  // quat -> matrix with s = 2/|q|^2 (absorbs scan drift, no sqrt)
  const float nrm = g.w*g.w + g.x*g.x + g.y*g.y + g.z*g.z;
  const float s2n = 2.0f * frcp(nrm);
  const float xs = g.x*s2n, ys = g.y*s2n, zs = g.z*s2n;
  const float wxm = g.w*xs, wym = g.w*ys, wzm = g.w*zs;
  const float xxm = g.x*xs, xym = g.x*ys, xzm = g.x*zs;
  const float yym = g.y*ys, yzm = g.y*zs, zzm = g.z*zs;
  const float m00 = 1.0f-(yym+zzm), m01 = xym-wzm,        m02 = xzm+wym;
  const float m10 = xym+wzm,        m11 = 1.0f-(xxm+zzm), m12 = yzm-wxm;
  const float m20 = xzm-wym,        m21 = yzm+wxm,        m22 = 1.0f-(xxm+yym);

  // ---- positions p_k = G.t + G.M * tl[k]  (in place) ----
  #pragma unroll
  for (int k = 0; k < CHUNK; ++k){
    const float tx = tlx[k], ty = tly[k], tz = tlz[k];
    tlx[k] = gtx + m00*tx + m01*ty + m02*tz;
    tly[k] = gty + m10*tx + m11*ty + m12*tz;
    tlz[k] = gtz + m20*tx + m21*ty + m22*tz;
  }

  // ---- pred publishes positions (pitch 25 -> conflict-free) ----
  if (c == 0){
    #pragma unroll
    for (int k = 0; k < CHUNK; ++k){
      if (j0 + k < NSTEP){
        const int o = lid*25 + 3*k;
        pos[o] = tlx[k]; pos[o+1] = tly[k]; pos[o+2] = tlz[k];
      }
    }
    if (lid == 0){ ini[0] = a1x; ini[1] = a2x; ini[2] = a2y; }
  }
  __syncthreads();

  // ---- targ waves: diff + reduce ----
  float acc = 0.0f;
  if (c == 1){
    if (lid == 0){
      const float dx = ini[0] - a1x;   // a1 differs only in x; a0 diff = 0
      const float dy = ini[1] - a2x;   // a2 differs in x,y (z = 0)
      const float dz = ini[2] - a2y;
      acc = dx*dx + dy*dy + dz*dz;
    }
    #pragma unroll
    for (int k = 0; k < CHUNK; ++k){
      if (j0 + k < NSTEP){
        const int o = lid*25 + 3*k;
        const float dx = pos[o]   - tlx[k];
        const float dy = pos[o+1] - tly[k];
        const float dz = pos[o+2] - tlz[k];
        acc = fmaf(dx, dx, acc);
        acc = fmaf(dy, dy, acc);
        acc = fmaf(dz, dz, acc);
      }
    }
    #pragma unroll
    for (int off = 32; off > 0; off >>= 1) acc += __shfl_down(acc, off);
    if (half == 1 && ln == 0) part = acc;   // wv3 partial
  }
  __syncthreads();
  if (wv == 2 && ln == 0) atomicAdd(out, (acc + part) * INVMEAN);  // 1 atomic/block
}

extern "C" void kernel_launch(void* const* d_in, const int* in_sizes, int n_in,
                              void* d_out, int out_size, void* d_ws, size_t ws_size,
                              hipStream_t stream) {
  const float* pred = (const float*)d_in[0];
  const float* targ = (const float*)d_in[1];
  float* out = (float*)d_out;

  hipMemsetAsync(d_out, 0, sizeof(float), stream);
  rmsd_kernel<<<NROW, 256, 0, stream>>>(pred, targ, out);
}